// Round 9
// baseline (359.942 us; speedup 1.0000x reference)
//
#include <hip/hip_runtime.h>
#include <math.h>

constexpr float DXC    = 3.125f;                              // 400/128
constexpr float INV_DX = 0.32f;                               // 1/3.125
constexpr float XMINC  = -200.0f;
constexpr float KW2    = 9.0f * 3.14159265358979323846f;      // cutoff^2 (mm^2)
constexpr float DXC2   = DXC * DXC;                           // 9.765625
constexpr float KW2C   = KW2 / DXC2;                          // cutoff^2 in cell^2
constexpr float NEGL2C = -(2.0f / KW2) * 1.4426950408889634f * DXC2; // exp2 scale (cell^2)
constexpr float WOFF   = 1.7983f;                             // window anchor offset
constexpr float WMIN   = 0.13533528323661270f;                // e^-2: gate in product space

constexpr int TPB    = 1024;
constexpr int LPB    = 1024;   // LORs per thread-slot group
constexpr int LPT    = 2;      // LORs per thread
constexpr int KSPLIT = 8;
constexpr int KCH    = 128 / KSPLIT;
constexpr int QTAB   = 1024;   // table bins over s in [0,4)

__device__ inline unsigned bf16_rn(float x) {
    unsigned u = __float_as_uint(x);
    return (u + 0x7fffu + ((u >> 16) & 1u)) >> 16;
}
__device__ inline unsigned pk_bf16(float x, float y) {
    return bf16_rn(x) | (bf16_rn(y) << 16);
}
__device__ inline float uaf(unsigned u) { return __uint_as_float(u); }

// ================= prep kernels =================
// V0[k][i][j]=img[k][i][j]; V1[k][i][j]=img[i][k][j]; V2[k][i][j]=img[i][j][k]
// S* = V* shifted by one bf16 within rows (flat +1; bleed never read, zeroed).
__global__ __launch_bounds__(256) void prep2_kernel(const float* __restrict__ img,
                                                    ushort* __restrict__ V0, ushort* __restrict__ V1,
                                                    ushort* __restrict__ V2, ushort* __restrict__ S0,
                                                    ushort* __restrict__ S1, ushort* __restrict__ S2) {
    int o = blockIdx.x * 256 + threadIdx.x;           // o = (a,b,c)
    int c = o & 127, b = (o >> 7) & 127, a = o >> 14;
    float x  = img[o];
    float xn = (c < 127) ? img[o + 1] : 0.0f;
    unsigned h  = bf16_rn(x);
    unsigned hn = bf16_rn(xn);
    V0[o] = (ushort)h;
    S0[o] = (ushort)((c < 127) ? hn : 0u);
    int p1 = (b << 14) | (a << 7) | c;
    V1[p1] = (ushort)h;
    S1[p1] = (ushort)((c < 127) ? hn : 0u);
    V2[o] = (ushort)bf16_rn(img[(b << 14) | (c << 7) | a]);
    S2[o] = (ushort)((c < 127) ? bf16_rn(img[(b << 14) | ((c + 1) << 7) | a]) : 0u);
}

__global__ __launch_bounds__(256) void prep_kernel(const float* __restrict__ img,
                                                   ushort* __restrict__ V0,
                                                   ushort* __restrict__ V1,
                                                   ushort* __restrict__ V2) {
    int o = blockIdx.x * 256 + threadIdx.x;
    float x = img[o];
    unsigned h = bf16_rn(x);
    V0[o] = (ushort)h;
    int c = o & 127, b = (o >> 7) & 127, a = o >> 14;
    V1[(b << 14) | (a << 7) | c] = (ushort)h;
    int j = o & 127, i = (o >> 7) & 127, k = o >> 14;
    V2[o] = (ushort)bf16_rn(img[(i << 14) | (j << 7) | k]);
}

__global__ __launch_bounds__(1024) void zero_kernel(float* __restrict__ out, int m) {
    int i = blockIdx.x * 1024 + threadIdx.x;
    if (i < m) out[i] = 0.0f;
}

// ================= staging =================
__device__ inline void stage_one(const ushort* __restrict__ V, int k, int tid, void* dst) {
    const char* src = (const char*)(V + ((size_t)k << 14));
    char* d = (char*)dst;
    int wbase = (tid >> 6) << 10;
    int lane16 = (tid & 63) << 4;
#pragma unroll
    for (int c = 0; c < 2; ++c) {
        int half = c << 14;
        __builtin_amdgcn_global_load_lds(
            (__attribute__((address_space(1))) void*)(const_cast<char*>(src + half + wbase + lane16)),
            (__attribute__((address_space(3))) void*)(d + half + wbase),
            16, 0, 0);
    }
}

// ================= v9: product-gate, 2 LOR/thread, twin single-buffer =================
struct WIN { float ea0, ea1, ea2, ea3, eb0, eb1, eb2, eb3; int adw; };
struct LST { float u, v, cu, cv, path; };

template <int AXIS>
__device__ inline LST lor_setup(const float* __restrict__ lors, int lorc, int k0) {
    const float* l = lors + (size_t)lorc * 6;
    float l0 = l[0], l1 = l[1], l2 = l[2], l3 = l[3], l4 = l[4], l5 = l[5];
    float p0x, p0y, p0z, p1x, p1y, p1z;
    if (AXIS == 0)      { p0x = l1; p0y = l2; p0z = l0; p1x = l4; p1y = l5; p1z = l3; }
    else if (AXIS == 1) { p0x = l0; p0y = l2; p0z = l1; p1x = l3; p1y = l5; p1z = l4; }
    else                { p0x = l0; p0y = l1; p0z = l2; p1x = l3; p1y = l4; p1z = l5; }
    float dvx = p1x - p0x, dvy = p1y - p0y, dvz = p1z - p0z;
    float L     = sqrtf(dvx * dvx + dvy * dvy + dvz * dvz);
    float invdz = 1.0f / dvz;
    LST s;
    s.path = DXC * L / fabsf(dvz);
    float dux  = dvx * INV_DX, ux0 = (p0x - XMINC) * INV_DX;
    float dvyS = dvy * INV_DX, vy0 = (p0y - XMINC) * INV_DX;
    float tz0 = -p0z * invdz;
    float dt = DXC * invdz;
    s.cu = dux * dt; s.cv = dvyS * dt;
    float zc0 = fmaf((float)k0, DXC, XMINC + 0.5f * DXC);
    float t0  = fmaf(zc0, invdz, tz0);
    s.u = fmaf(t0, dux, ux0);
    s.v = fmaf(t0, dvyS, vy0);
    return s;
}

__device__ inline WIN mkwin(float u, float v, const float4* wt) {
    WIN w;
    float e0f = fminf(fmaxf(floorf(v - WOFF), 0.0f), 124.0f);
    float i0f = fminf(fmaxf(floorf(u - WOFF), 0.0f), 124.0f);
    int qv = min((int)((v - e0f) * (QTAB / 4.0f)), QTAB - 1);
    int qu = min((int)((u - i0f) * (QTAB / 4.0f)), QTAB - 1);
    float4 eb = wt[qv];
    float4 ea = wt[qu];
    int e0 = (int)e0f, i0 = (int)i0f;
    // adw encodes row base + dword col + A/B-half select (B = +8192 dwords)
    w.adw = (i0 << 6) + (e0 >> 1) + ((e0 & 1) << 13);
    w.ea0 = ea.x; w.ea1 = ea.y; w.ea2 = ea.z; w.ea3 = ea.w;
    w.eb0 = eb.x; w.eb1 = eb.y; w.eb2 = eb.z; w.eb3 = eb.w;
    return w;
}

__device__ inline float do_slice(const WIN& w, const uint* __restrict__ sl, float acc) {
#pragma unroll
    for (int r = 0; r < 4; ++r) {
        int a = w.adw + (r << 6);
        uint d0 = sl[a], d1 = sl[a + 1];
        float x0 = uaf(d0 << 16), x1 = uaf(d0 & 0xffff0000u);
        float x2 = uaf(d1 << 16), x3 = uaf(d1 & 0xffff0000u);
        float er = (r == 0) ? w.ea0 : (r == 1) ? w.ea1 : (r == 2) ? w.ea2 : w.ea3;
        float p0 = er * w.eb0, p1 = er * w.eb1, p2 = er * w.eb2, p3 = er * w.eb3;
        p0 = (p0 >= WMIN) ? p0 : 0.0f;
        p1 = (p1 >= WMIN) ? p1 : 0.0f;
        p2 = (p2 >= WMIN) ? p2 : 0.0f;
        p3 = (p3 >= WMIN) ? p3 : 0.0f;
        acc = fmaf(p0, x0, acc);
        acc = fmaf(p1, x1, acc);
        acc = fmaf(p2, x2, acc);
        acc = fmaf(p3, x3, acc);
    }
    return acc;
}

template <int AXIS>
__device__ void proj_axis9(uint* sl, float4* wt,
                           const ushort* __restrict__ V, const ushort* __restrict__ S,
                           const float* __restrict__ lors,
                           float* __restrict__ out, int n, int blk, int ks)
{
    const int tid = threadIdx.x;
    int lor0 = blk * (LPT * LPB) + tid;
    int lor1 = lor0 + LPB;
    bool act0 = lor0 < n, act1 = lor1 < n;
    int lc0 = act0 ? lor0 : n - 1;
    int lc1 = act1 ? lor1 : n - 1;

    const int k0 = ks * KCH, k1 = k0 + KCH;
    LST s0 = lor_setup<AXIS>(lors, lc0, k0);
    LST s1 = lor_setup<AXIS>(lors, lc1, k0);
    float acc0 = 0.0f, acc1 = 0.0f;

    // prologue: stage slice k0 (A then B at +8192 dwords), fill table
    stage_one(V, k0, tid, sl);
    stage_one(S, k0, tid, sl + 8192);
    {
        float s = ((float)tid + 0.5f) * (4.0f / (float)QTAB);
        float4 e;
        float o0 = 0.5f - s, o1 = 1.5f - s, o2 = 2.5f - s, o3 = 3.5f - s;
        e.x = exp2f(o0 * o0 * NEGL2C);
        e.y = exp2f(o1 * o1 * NEGL2C);
        e.z = exp2f(o2 * o2 * NEGL2C);
        e.w = exp2f(o3 * o3 * NEGL2C);
        wt[tid] = e;
    }
    __syncthreads();   // table ready AND slice k0 DMA drained

    WIN w0 = mkwin(s0.u, s0.v, wt);
    WIN w1 = mkwin(s1.u, s1.v, wt);

    for (int k = k0; k < k1; ++k) {
        acc0 = do_slice(w0, sl, acc0);
        acc1 = do_slice(w1, sl, acc1);

        if (k < k1 - 1) {
            s0.u += s0.cu; s0.v += s0.cv;
            s1.u += s1.cu; s1.v += s1.cv;
            __syncthreads();                 // everyone done reading slice k
            stage_one(V, k + 1, tid, sl);    // issue DMA for slice k+1
            stage_one(S, k + 1, tid, sl + 8192);
            w0 = mkwin(s0.u, s0.v, wt);      // VALU + table reads: overlap DMA
            w1 = mkwin(s1.u, s1.v, wt);
            __syncthreads();                 // DMA drained -> slice k+1 ready
        }
    }

    if (act0) atomicAdd(out + lor0, acc0 * s0.path);
    if (act1) atomicAdd(out + lor1, acc1 * s1.path);
}

__global__ __launch_bounds__(TPB, 2) void proj_fused9(const ushort* __restrict__ V0,
                                                      const ushort* __restrict__ V1,
                                                      const ushort* __restrict__ V2,
                                                      const ushort* __restrict__ S0,
                                                      const ushort* __restrict__ S1,
                                                      const ushort* __restrict__ S2,
                                                      const float* __restrict__ xl,
                                                      const float* __restrict__ yl,
                                                      const float* __restrict__ zl,
                                                      float* __restrict__ out,
                                                      int n, int nblk)
{
    __shared__ uint   sl[16384];     // 64 KiB: A slice (32K) + B shifted slice (32K)
    __shared__ float4 wt[QTAB];      // 16 KiB weight table
    int per = nblk * KSPLIT;
    int axis = blockIdx.x / per;
    int r = blockIdx.x - axis * per;
    int blk = r >> 3;                // KSPLIT = 8
    int ks  = r & 7;
    if (axis == 0)      proj_axis9<0>(sl, wt, V0, S0, xl, out, n, blk, ks);
    else if (axis == 1) proj_axis9<1>(sl, wt, V1, S1, yl, out + n, n, blk, ks);
    else                proj_axis9<2>(sl, wt, V2, S2, zl, out + 2 * (size_t)n, n, blk, ks);
}

// ================= v7 fallback (chains + alignbit, dbuf) =================
template <int AXIS>
__device__ inline void stage_issue(const float* __restrict__ img, int k, int tid,
                                   float4 st[4]) {
#pragma unroll
    for (int c = 0; c < 4; ++c) {
        int f4 = tid + TPB * c;
        int fl = f4 << 2;
        if (AXIS == 2) {
            int i = fl >> 7, j = fl & 127;
            const float* p = img + (i << 14) + (j << 7) + k;
            st[c] = make_float4(p[0], p[128], p[256], p[384]);
        } else {
            int off;
            if (AXIS == 1) off = ((fl >> 7) << 14) | (k << 7) | (fl & 127);
            else           off = (k << 14) | fl;
            st[c] = *reinterpret_cast<const float4*>(img + off);
        }
    }
}

__device__ inline void stage_write(const float4 st[4], ushort* slb, int tid) {
    uint* w = reinterpret_cast<uint*>(slb);
#pragma unroll
    for (int c = 0; c < 4; ++c) {
        int f4 = tid + TPB * c;
        w[f4 * 2]     = pk_bf16(st[c].x, st[c].y);
        w[f4 * 2 + 1] = pk_bf16(st[c].z, st[c].w);
    }
}

template <int AXIS, bool PRE>
__device__ void proj_axis7(ushort (*sl)[16384], float4* wtab,
                           const ushort* __restrict__ V,
                           const float*  __restrict__ imgF,
                           const float*  __restrict__ lors,
                           float* __restrict__ out, int n, int blk, int ks)
{
    const int tid = threadIdx.x;
    const int lor = blk * LPB + tid;
    const bool active = lor < n;
    const int lorc = active ? lor : n - 1;

    const int k0 = ks * KCH, k1 = k0 + KCH;
    LST s = lor_setup<AXIS>(lors, lorc, k0);
    float u = s.u, v = s.v, cu = s.cu, cv = s.cv;
    float acc = 0.0f;

    if (PRE) {
        stage_one(V, k0, tid, sl[k0 & 1]);
    } else {
        float4 st[4];
        stage_issue<AXIS>(imgF, k0, tid, st);
        stage_write(st, sl[k0 & 1], tid);
    }
    {
        float sx = ((float)tid + 0.5f) * (4.0f / (float)QTAB);
        float4 e;
        float o0 = 0.5f - sx, o1 = 1.5f - sx, o2 = 2.5f - sx, o3 = 3.5f - sx;
        e.x = exp2f(o0 * o0 * NEGL2C);
        e.y = exp2f(o1 * o1 * NEGL2C);
        e.z = exp2f(o2 * o2 * NEGL2C);
        e.w = exp2f(o3 * o3 * NEGL2C);
        wtab[tid] = e;
    }
    __syncthreads();

    for (int k = k0; k < k1; ++k) {
        const ushort* sbuf = sl[k & 1];
        float4 st2[4];
        if (k < k1 - 1) {
            if (PRE) stage_one(V, k + 1, tid, sl[(k & 1) ^ 1]);
            else     stage_issue<AXIS>(imgF, k + 1, tid, st2);
        }

        float e0f = fminf(fmaxf(floorf(v - WOFF), 0.0f), 124.0f);
        int   e0  = (int)e0f;
        int   qv  = min((int)((v - e0f) * (QTAB / 4.0f)), QTAB - 1);
        float4 eb = wtab[qv];
        float i0f = fminf(fmaxf(floorf(u - WOFF), 0.0f), 124.0f);
        int   i0c = (int)i0f;
        int   qu  = min((int)((u - i0f) * (QTAB / 4.0f)), QTAB - 1);
        float4 ea = wtab[qu];
        float eaa[4] = {ea.x, ea.y, ea.z, ea.w};

        const uint* s32 = reinterpret_cast<const uint*>(sbuf);
        int dwc = e0 >> 1;
        int sh  = (e0 & 1) << 4;
        int rowdw = (i0c << 6) + dwc;
#pragma unroll
        for (int r = 0; r < 4; ++r) {
            const uint* sr = s32 + rowdw + (r << 6);
            uint d0 = sr[0], d1 = sr[1], d2 = sr[2];
            uint p01 = __builtin_amdgcn_alignbit(d1, d0, sh);
            uint p23 = __builtin_amdgcn_alignbit(d2, d1, sh);
            float x0 = uaf(p01 << 16);
            float x1 = uaf(p01 & 0xffff0000u);
            float x2 = uaf(p23 << 16);
            float x3 = uaf(p23 & 0xffff0000u);
            float er = eaa[r];
            float p0 = er * eb.x, p1 = er * eb.y, p2 = er * eb.z, p3 = er * eb.w;
            p0 = (p0 >= WMIN) ? p0 : 0.0f;
            p1 = (p1 >= WMIN) ? p1 : 0.0f;
            p2 = (p2 >= WMIN) ? p2 : 0.0f;
            p3 = (p3 >= WMIN) ? p3 : 0.0f;
            acc = fmaf(p0, x0, acc);
            acc = fmaf(p1, x1, acc);
            acc = fmaf(p2, x2, acc);
            acc = fmaf(p3, x3, acc);
        }

        u += cu; v += cv;

        if (k < k1 - 1) {
            if (!PRE) stage_write(st2, sl[(k & 1) ^ 1], tid);
            __syncthreads();
        }
    }

    if (active) atomicAdd(out + lor, acc * s.path);
}

template <bool PRE>
__global__ __launch_bounds__(TPB, 2) void proj_fused7(const float* __restrict__ img,
                                                      const ushort* __restrict__ V0,
                                                      const ushort* __restrict__ V1,
                                                      const ushort* __restrict__ V2,
                                                      const float* __restrict__ xl,
                                                      const float* __restrict__ yl,
                                                      const float* __restrict__ zl,
                                                      float* __restrict__ out,
                                                      int n, int nblk)
{
    __shared__ ushort sl[2][16384];
    __shared__ float4 wtab[QTAB];
    int per = nblk * KSPLIT;
    int axis = blockIdx.x / per;
    int r = blockIdx.x - axis * per;
    int blk = r >> 3;
    int ks  = r & 7;
    if (axis == 0)      proj_axis7<0, PRE>(sl, wtab, V0, img, xl, out, n, blk, ks);
    else if (axis == 1) proj_axis7<1, PRE>(sl, wtab, V1, img, yl, out + n, n, blk, ks);
    else                proj_axis7<2, PRE>(sl, wtab, V2, img, zl, out + 2 * (size_t)n, n, blk, ks);
}

extern "C" void kernel_launch(void* const* d_in, const int* in_sizes, int n_in,
                              void* d_out, int out_size, void* d_ws, size_t ws_size,
                              hipStream_t stream) {
    const float* img   = (const float*)d_in[0];
    const float* xlors = (const float*)d_in[1];
    const float* ylors = (const float*)d_in[2];
    const float* zlors = (const float*)d_in[3];
    float* out = (float*)d_out;

    int n = in_sizes[1] / 6;
    int m = 3 * n;

    zero_kernel<<<(m + 1023) / 1024, 1024, 0, stream>>>(out, m);

    constexpr size_t VOL = 128 * 128 * 128;

    if (ws_size >= 6 * VOL * sizeof(ushort)) {
        int nblk = (n + LPT * LPB - 1) / (LPT * LPB);
        int grid = 3 * nblk * KSPLIT;
        ushort* V0 = (ushort*)d_ws;
        ushort* V1 = V0 + VOL;  ushort* V2 = V1 + VOL;
        ushort* S0 = V2 + VOL;  ushort* S1 = S0 + VOL;  ushort* S2 = S1 + VOL;
        prep2_kernel<<<VOL / 256, 256, 0, stream>>>(img, V0, V1, V2, S0, S1, S2);
        proj_fused9<<<grid, TPB, 0, stream>>>(V0, V1, V2, S0, S1, S2,
                                              xlors, ylors, zlors, out, n, nblk);
    } else if (ws_size >= 3 * VOL * sizeof(ushort)) {
        int nblk = (n + LPB - 1) / LPB;
        int grid = 3 * nblk * KSPLIT;
        ushort* V0 = (ushort*)d_ws;
        ushort* V1 = V0 + VOL;  ushort* V2 = V1 + VOL;
        prep_kernel<<<VOL / 256, 256, 0, stream>>>(img, V0, V1, V2);
        proj_fused7<true><<<grid, TPB, 0, stream>>>(img, V0, V1, V2,
                                                    xlors, ylors, zlors, out, n, nblk);
    } else {
        int nblk = (n + LPB - 1) / LPB;
        int grid = 3 * nblk * KSPLIT;
        proj_fused7<false><<<grid, TPB, 0, stream>>>(img, nullptr, nullptr, nullptr,
                                                     xlors, ylors, zlors, out, n, nblk);
    }
}